// Round 26
// baseline (117.742 us; speedup 1.0000x reference)
//
#include <hip/hip_runtime.h>
#include <stdint.h>

#define B2 128
#define NSEQ 256
#define DIM 256
#define NH 8
#define CH 32

typedef __attribute__((ext_vector_type(8))) __bf16 bf16x8;
typedef __attribute__((ext_vector_type(8))) unsigned short u16x8;
typedef __attribute__((ext_vector_type(4))) unsigned short u16x4;
typedef __attribute__((ext_vector_type(4))) unsigned int u32x4;
typedef __attribute__((ext_vector_type(4))) float f32x4;

__device__ __forceinline__ unsigned short f2bf(float f) {
  unsigned int u = __builtin_bit_cast(unsigned int, f);
  u += 0x7FFFu + ((u >> 16) & 1u);
  return (unsigned short)(u >> 16);
}
__device__ __forceinline__ float bf2f(unsigned short h) {
  unsigned int u = ((unsigned int)h) << 16;
  return __builtin_bit_cast(float, u);
}
__device__ __forceinline__ bf16x8 as_bf(u16x8 v) { return __builtin_bit_cast(bf16x8, v); }

__device__ __forceinline__ void gload16(void* lds, const void* g) {
  __builtin_amdgcn_global_load_lds(
      (__attribute__((address_space(1))) void*)(g),
      (__attribute__((address_space(3))) void*)(lds), 16, 0, 0);
}

// ---------------- K0: fp32 -> bf16 conversion (x + weights + nb) ----------------
__global__ void k_convert(const float* __restrict__ x, const float* __restrict__ wqkv,
                          const float* __restrict__ wgate, const float* __restrict__ wo,
                          const float* __restrict__ nb,
                          unsigned short* __restrict__ xb, unsigned short* __restrict__ wallb,
                          unsigned short* __restrict__ wob, unsigned short* __restrict__ nbb) {
  const int NX = 8388608, NWALL = 262144, NWO = 65536, NNB = 524288;
  int i = blockIdx.x * blockDim.x + threadIdx.x;
  int total4 = (NX + NWALL + NWO + NNB) >> 2;
  if (i >= total4) return;
  int e = i << 2;
  float4 v;
  unsigned short* dst;
  if (e < NX) {
    v = *reinterpret_cast<const float4*>(x + e);
    dst = xb + e;
  } else if (e < NX + NWALL) {
    int o = e - NX;
    v = (o < 196608) ? *reinterpret_cast<const float4*>(wqkv + o)
                     : *reinterpret_cast<const float4*>(wgate + (o - 196608));
    dst = wallb + o;
  } else if (e < NX + NWALL + NWO) {
    int o = e - NX - NWALL;
    v = *reinterpret_cast<const float4*>(wo + o);
    dst = wob + o;
  } else {
    int o = e - NX - NWALL - NWO;
    v = *reinterpret_cast<const float4*>(nb + o);
    dst = nbb + o;
  }
  u16x4 r;
  r[0] = f2bf(v.x); r[1] = f2bf(v.y); r[2] = f2bf(v.z); r[3] = f2bf(v.w);
  *reinterpret_cast<u16x4*>(dst) = r;
}

// ---------------- K1: QKV+gate GEMM, BM=128 BN=256, 512 threads (2x4 waves) ----------------
// 1D grid + chunked XCD swizzle: orig=(bid&7)*128+(bid>>3) -> each XCD handles
// its 32 m-tiles with the 4 n-variants consecutively (A-tile L2-hot on reuse).
// Row-pair LDS (conflicts 0), double-buffered single-barrier loop, transpose epilogue.
__launch_bounds__(512, 3)
__global__ void k_gemm0(const unsigned short* __restrict__ Ab, const unsigned short* __restrict__ Bw,
                        unsigned short* __restrict__ qs, unsigned short* __restrict__ ksb,
                        unsigned short* __restrict__ vsb, unsigned short* __restrict__ gateb,
                        const float* __restrict__ gbias) {
  __shared__ __attribute__((aligned(16))) char smem[49152];  // As 2x8KB | Bs 2x16KB; epilogue overlay
  const int tid = threadIdx.x, lane = tid & 63, w = tid >> 6;
  const int wr = w >> 2, wc = w & 3;
  const int l15 = lane & 15, hi = lane >> 4;
  const int bid = blockIdx.x;
  const int orig = (bid & 7) * 128 + (bid >> 3);  // bijective: 1024 % 8 == 0
  const int m0 = (orig >> 2) * 128;
  const int which = orig & 3;
  const int n0 = which * 256;

  auto stageA = [&](int buf, int k0) {
    char* sbuf = buf ? smem + 8192 : smem;
    int i = tid;                      // chunk i covers LDS byte i*16
    int rp = i >> 3, sp = i & 7;
    int sl = sp ^ (rp & 7);
    int row = 2 * rp + (sl >> 2), s3 = sl & 3;
    const unsigned short* g = Ab + (size_t)(m0 + row) * 256 + k0 + s3 * 8;
    gload16(sbuf + w * 1024, g);
  };
  auto stageB = [&](int buf, int k0) {
    char* sbuf = buf ? smem + 32768 : smem + 16384;
#pragma unroll
    for (int q2 = 0; q2 < 2; ++q2) {
      int i = q2 * 512 + tid;
      int rp = i >> 3, sp = i & 7;
      int sl = sp ^ (rp & 7);
      int row = 2 * rp + (sl >> 2), s3 = sl & 3;
      const unsigned short* g = Bw + (size_t)(n0 + row) * 256 + k0 + s3 * 8;
      gload16(sbuf + q2 * 8192 + w * 1024, g);
    }
  };

  f32x4 acc[4][4];
#pragma unroll
  for (int i = 0; i < 4; ++i) {
#pragma unroll
    for (int j = 0; j < 4; ++j) acc[i][j] = (f32x4){0.f, 0.f, 0.f, 0.f};
  }

  stageA(0, 0);
  stageB(0, 0);

#pragma unroll
  for (int kt = 0; kt < 8; ++kt) {
    const int cur = kt & 1;
    asm volatile("s_waitcnt vmcnt(0)" ::: "memory");
    __builtin_amdgcn_sched_barrier(0);
    __builtin_amdgcn_s_barrier();
    __builtin_amdgcn_sched_barrier(0);
    if (kt < 7) {
      stageA(cur ^ 1, (kt + 1) * 32);
      stageB(cur ^ 1, (kt + 1) * 32);
    }
    {
      const char* Acur = cur ? smem + 8192 : smem;
      const char* Bcur = cur ? smem + 32768 : smem + 16384;
      bf16x8 af[4], bfv[4];
#pragma unroll
      for (int fr = 0; fr < 4; ++fr) {
        int ra = wr * 64 + fr * 16 + l15;
        int rp = ra >> 1;
        int sl = ((ra & 1) << 2) | hi;
        int off = rp * 128 + (sl ^ (rp & 7)) * 16;
        af[fr] = *reinterpret_cast<const bf16x8*>(Acur + off);
      }
#pragma unroll
      for (int fc = 0; fc < 4; ++fc) {
        int rb = wc * 64 + fc * 16 + l15;
        int rp = rb >> 1;
        int sl = ((rb & 1) << 2) | hi;
        int off = rp * 128 + (sl ^ (rp & 7)) * 16;
        bfv[fc] = *reinterpret_cast<const bf16x8*>(Bcur + off);
      }
#pragma unroll
      for (int fr = 0; fr < 4; ++fr) {
#pragma unroll
        for (int fc = 0; fc < 4; ++fc)
          acc[fr][fc] = __builtin_amdgcn_mfma_f32_16x16x32_bf16(af[fr], bfv[fc], acc[fr][fc], 0, 0, 0);
      }
    }
  }

  // ---- epilogue: transpose through LDS, coalesced 16B stores ----
  unsigned short* ep = reinterpret_cast<unsigned short*>(smem);  // [64][264] bf16
  float gb4[4];
  if (which == 3) {
#pragma unroll
    for (int fc = 0; fc < 4; ++fc) gb4[fc] = gbias[wc * 64 + fc * 16 + l15];
  }
  unsigned short* dstbuf = (which == 0) ? qs : (which == 1) ? ksb : (which == 2) ? vsb : gateb;
#pragma unroll
  for (int half = 0; half < 2; ++half) {
    __syncthreads();  // prior smem readers (K-loop / prev half) done
    if (wr == half) {
#pragma unroll
      for (int fr = 0; fr < 4; ++fr) {
#pragma unroll
        for (int fc = 0; fc < 4; ++fc) {
          int col = wc * 64 + fc * 16 + l15;
#pragma unroll
          for (int i = 0; i < 4; ++i) {
            float v = acc[fr][fc][i];
            if (which == 0) v *= 0.17677669529663687f;  // C^-0.5
            if (which == 3) v = 1.0f / (1.0f + __expf(-(v + gb4[fc])));
            ep[(fr * 16 + (hi << 2) + i) * 264 + col] = f2bf(v);
          }
        }
      }
    }
    __syncthreads();
    const int row = tid >> 3, hh = tid & 7;
    const int mrow2 = m0 + half * 64 + row;
    const int b = mrow2 >> 8, n = mrow2 & 255;
    unsigned short* dst = dstbuf + ((size_t)(b * 8 + hh) * 256 + n) * 32;
    const unsigned short* src = ep + row * 264 + hh * 32;
#pragma unroll
    for (int q4 = 0; q4 < 4; ++q4)
      *reinterpret_cast<u16x8*>(dst + q4 * 8) = *reinterpret_cast<const u16x8*>(src + q4 * 8);
  }
}

// ---------------- K3: output GEMM (byte-identical — control) ----------------
__launch_bounds__(256, 4)
__global__ void k_gemm1(const unsigned short* __restrict__ Ab, const unsigned short* __restrict__ Bw,
                        float* __restrict__ outp, const float* __restrict__ bo) {
  __shared__ __attribute__((aligned(16))) char As[2][8192];
  __shared__ __attribute__((aligned(16))) char Bs[2][8192];
  const int tid = threadIdx.x, lane = tid & 63, w = tid >> 6;
  const int wr = w >> 1, wc = w & 1;
  const int l15 = lane & 15, hi = lane >> 4;
  const int m0 = blockIdx.x * 128, n0 = blockIdx.y * 128;

  auto stage_pair = [&](char* sbuf, const unsigned short* gsrc, int row0, int k0) {
#pragma unroll
    for (int q2 = 0; q2 < 2; ++q2) {
      int i = q2 * 256 + tid;
      int rp = i >> 3, sp = i & 7;
      int sl = sp ^ (rp & 7);
      int row = 2 * rp + (sl >> 2), s3 = sl & 3;
      const unsigned short* g = gsrc + (size_t)(row0 + row) * 256 + k0 + s3 * 8;
      gload16(sbuf + q2 * 4096 + w * 1024, g);
    }
  };

  f32x4 acc[4][4];
#pragma unroll
  for (int i = 0; i < 4; ++i) {
#pragma unroll
    for (int j = 0; j < 4; ++j) acc[i][j] = (f32x4){0.f, 0.f, 0.f, 0.f};
  }

  stage_pair(As[0], Ab, m0, 0);
  stage_pair(Bs[0], Bw, n0, 0);

#pragma unroll
  for (int kt = 0; kt < 8; ++kt) {
    const int cur = kt & 1;
    asm volatile("s_waitcnt vmcnt(0)" ::: "memory");
    __builtin_amdgcn_sched_barrier(0);
    __builtin_amdgcn_s_barrier();
    __builtin_amdgcn_sched_barrier(0);
    if (kt < 7) {
      stage_pair(As[cur ^ 1], Ab, m0, (kt + 1) * 32);
      stage_pair(Bs[cur ^ 1], Bw, n0, (kt + 1) * 32);
    }
    {
      bf16x8 af[4], bfv[4];
#pragma unroll
      for (int fr = 0; fr < 4; ++fr) {
        int ra = wr * 64 + fr * 16 + l15;
        int rp = ra >> 1;
        int sl = ((ra & 1) << 2) | hi;
        int off = rp * 128 + (sl ^ (rp & 7)) * 16;
        af[fr] = *reinterpret_cast<const bf16x8*>(As[cur] + off);
      }
#pragma unroll
      for (int fc = 0; fc < 4; ++fc) {
        int rb = wc * 64 + fc * 16 + l15;
        int rp = rb >> 1;
        int sl = ((rb & 1) << 2) | hi;
        int off = rp * 128 + (sl ^ (rp & 7)) * 16;
        bfv[fc] = *reinterpret_cast<const bf16x8*>(Bs[cur] + off);
      }
#pragma unroll
      for (int fr = 0; fr < 4; ++fr) {
#pragma unroll
        for (int fc = 0; fc < 4; ++fc)
          acc[fr][fc] = __builtin_amdgcn_mfma_f32_16x16x32_bf16(af[fr], bfv[fc], acc[fr][fc], 0, 0, 0);
      }
    }
  }

#pragma unroll
  for (int fr = 0; fr < 4; ++fr) {
    int mrow = m0 + wr * 64 + fr * 16 + (hi << 2);
#pragma unroll
    for (int fc = 0; fc < 4; ++fc) {
      int e = n0 + wc * 64 + fc * 16 + l15;
      float bb = bo[e];
#pragma unroll
      for (int i = 0; i < 4; ++i)
        outp[(size_t)(mrow + i) * 256 + e] = acc[fr][fc][i] + bb;
    }
  }
}

// ---------------- K2: attention per (b2, head), 512 threads = 8 waves ----------------
// qf + gate loads for BOTH fr hoisted before __syncthreads (hidden under K/V
// staging); fr loop fully unrolled so [fr] indexing folds to registers.
__launch_bounds__(512, 2)
__global__ void k_attn(const unsigned short* __restrict__ qs, const unsigned short* __restrict__ ksb,
                       const unsigned short* __restrict__ vsb, const unsigned short* __restrict__ gateb,
                       const float* __restrict__ mask, const unsigned short* __restrict__ nbb,
                       unsigned short* __restrict__ wag) {
  __shared__ __attribute__((aligned(16))) unsigned short vt[32][264];     // V^T [c][key]
  __shared__ __attribute__((aligned(16))) unsigned short pch[8][16][72];  // per-wave P chunk
  __shared__ __attribute__((aligned(16))) unsigned short Kl[16][64][8];   // K frags, lane-linear
  __shared__ __attribute__((aligned(16))) float mb[256];
  __shared__ float invl[8][16];
  const int tid = threadIdx.x, lane = tid & 63, w = tid >> 6;
  const int l15 = lane & 15, hi = lane >> 4;
  const int b = blockIdx.x, h = blockIdx.y;
  const size_t bh = (size_t)(b * 8 + h);
  const unsigned short* kbase = ksb + bh * 8192;
  const unsigned short* vbase = vsb + bh * 8192;
  const unsigned short* qbase = qs + bh * 8192;
  const unsigned short* nbh = nbb + (size_t)h * 65536;

  if (tid < 256) {
    mb[tid] = 1e9f * (mask[b * 256 + tid] - 1.0f);
    const unsigned short* vrow = vbase + tid * 32;
#pragma unroll
    for (int c0 = 0; c0 < 32; c0 += 8) {
      u16x8 vv = *reinterpret_cast<const u16x8*>(vrow + c0);
#pragma unroll
      for (int j = 0; j < 8; ++j) vt[c0 + j][tid] = vv[j];
    }
  } else {
    const int key = tid - 256;
    const unsigned short* krow = kbase + key * 32;
#pragma unroll
    for (int c8 = 0; c8 < 4; ++c8)
      *reinterpret_cast<u16x8*>(&Kl[key >> 4][c8 * 16 + (key & 15)][0]) =
          *reinterpret_cast<const u16x8*>(krow + c8 * 8);
  }

  // hoisted q / gate loads for both fr (latency hidden under staging + barrier)
  u16x8 qfv[2], gv[2];
#pragma unroll
  for (int f = 0; f < 2; ++f) {
    const int q0 = w * 32 + f * 16;
    qfv[f] = *reinterpret_cast<const u16x8*>(qbase + (q0 + l15) * 32 + hi * 8);
    gv[f] = *reinterpret_cast<const u16x8*>(gateb + bh * 8192 + (q0 + (lane >> 2)) * 32 + (lane & 3) * 8);
  }
  __syncthreads();

  const f32x4 zero = {0.f, 0.f, 0.f, 0.f};
#pragma unroll
  for (int fr = 0; fr < 2; ++fr) {
    const int q0 = w * 32 + fr * 16;
    const u16x8 qf = qfv[fr];

    // nb prefetch (bf16, 32 VGPRs) — issued before the MFMA cluster
    const unsigned short* nbq = nbh + (size_t)(q0 + l15) * 256;
    u16x4 nbv[16];
#pragma unroll
    for (int kt = 0; kt < 16; ++kt)
      nbv[kt] = *reinterpret_cast<const u16x4*>(nbq + kt * 16 + hi * 4);

    f32x4 sacc[16];
    __builtin_amdgcn_s_setprio(1);
#pragma unroll
    for (int kt = 0; kt < 16; ++kt) {
      bf16x8 kf = *reinterpret_cast<const bf16x8*>(&Kl[kt][lane][0]);
      sacc[kt] = __builtin_amdgcn_mfma_f32_16x16x32_bf16(kf, as_bf(qf), zero, 0, 0, 0);
    }
    __builtin_amdgcn_s_setprio(0);

#pragma unroll
    for (int kt = 0; kt < 16; ++kt) {
      float4 mb4 = *reinterpret_cast<const float4*>(&mb[kt * 16 + hi * 4]);
      sacc[kt][0] += mb4.x + bf2f(nbv[kt][0]);
      sacc[kt][1] += mb4.y + bf2f(nbv[kt][1]);
      sacc[kt][2] += mb4.z + bf2f(nbv[kt][2]);
      sacc[kt][3] += mb4.w + bf2f(nbv[kt][3]);
    }
    float mx = -3.0e38f;
#pragma unroll
    for (int kt = 0; kt < 16; ++kt) {
#pragma unroll
      for (int i = 0; i < 4; ++i) mx = fmaxf(mx, sacc[kt][i]);
    }
    mx = fmaxf(mx, __shfl_xor(mx, 16));
    mx = fmaxf(mx, __shfl_xor(mx, 32));

    float sum = 0.f;
    f32x4 wacc[2];
    wacc[0] = zero; wacc[1] = zero;
#pragma unroll
    for (int c = 0; c < 4; ++c) {
#pragma unroll
      for (int ktl = 0; ktl < 4; ++ktl) {
        const int kt = c * 4 + ktl;
        u16x4 pv;
#pragma unroll
        for (int i = 0; i < 4; ++i) {
          float p = __expf(sacc[kt][i] - mx);
          sum += p;
          pv[i] = f2bf(p);  // unnormalized; inv folded into epilogue
        }
        *reinterpret_cast<u16x4*>(&pch[w][l15][ktl * 16 + hi * 4]) = pv;
      }
      asm volatile("" ::: "memory");  // compile-time order: pch writes before pa reads
      __builtin_amdgcn_s_setprio(1);
#pragma unroll
      for (int ks2 = 0; ks2 < 2; ++ks2) {
        bf16x8 pa = *reinterpret_cast<const bf16x8*>(&pch[w][l15][ks2 * 32 + hi * 8]);
#pragma unroll
        for (int ct = 0; ct < 2; ++ct) {
          bf16x8 vb = *reinterpret_cast<const bf16x8*>(&vt[ct * 16 + l15][c * 64 + ks2 * 32 + hi * 8]);
          wacc[ct] = __builtin_amdgcn_mfma_f32_16x16x32_bf16(pa, vb, wacc[ct], 0, 0, 0);
        }
      }
      __builtin_amdgcn_s_setprio(0);
    }
    sum += __shfl_xor(sum, 16);
    sum += __shfl_xor(sum, 32);
    const float inv = 1.0f / sum;
    if (hi == 0) invl[w][l15] = inv;

    // Epilogue: transpose wacc through LDS (reuse pch[w] as [16][36] f32)
    asm volatile("" ::: "memory");  // order: pa reads before et overwrites
    float* et = reinterpret_cast<float*>(&pch[w][0][0]);
#pragma unroll
    for (int ct = 0; ct < 2; ++ct) {
#pragma unroll
      for (int i = 0; i < 4; ++i)
        et[(hi * 4 + i) * 36 + ct * 16 + l15] = wacc[ct][i];
    }
    asm volatile("" ::: "memory");  // order: et writes before et reads
    const int eq = lane >> 2, eh = lane & 3;
    float4 v0 = *reinterpret_cast<const float4*>(&et[eq * 36 + eh * 8]);
    float4 v1 = *reinterpret_cast<const float4*>(&et[eq * 36 + eh * 8 + 4]);
    const float iv = invl[w][eq];
    const int qrow = q0 + eq;
    u16x8 g = gv[fr];
    u16x8 ov;
    ov[0] = f2bf(bf2f(g[0]) * v0.x * iv);
    ov[1] = f2bf(bf2f(g[1]) * v0.y * iv);
    ov[2] = f2bf(bf2f(g[2]) * v0.z * iv);
    ov[3] = f2bf(bf2f(g[3]) * v0.w * iv);
    ov[4] = f2bf(bf2f(g[4]) * v1.x * iv);
    ov[5] = f2bf(bf2f(g[5]) * v1.y * iv);
    ov[6] = f2bf(bf2f(g[6]) * v1.z * iv);
    ov[7] = f2bf(bf2f(g[7]) * v1.w * iv);
    *reinterpret_cast<u16x8*>(wag + ((size_t)(b * 256 + qrow)) * 256 + h * 32 + eh * 8) = ov;
    asm volatile("" ::: "memory");  // order: et reads before next fr's pch writes
  }
}

extern "C" void kernel_launch(void* const* d_in, const int* in_sizes, int n_in,
                              void* d_out, int out_size, void* d_ws, size_t ws_size,
                              hipStream_t stream) {
  const float* x     = (const float*)d_in[0];
  const float* mask  = (const float*)d_in[1];
  const float* nb    = (const float*)d_in[2];
  const float* wqkv  = (const float*)d_in[3];
  const float* wgate = (const float*)d_in[4];
  const float* gbias = (const float*)d_in[5];
  const float* wo    = (const float*)d_in[6];
  const float* bo    = (const float*)d_in[7];
  float* outp = (float*)d_out;

  char* ws = (char*)d_ws;
  unsigned short* xb    = (unsigned short*)(ws);               // 16,777,216 B
  unsigned short* wallb = (unsigned short*)(ws + 16777216);    //    524,288 B
  unsigned short* wob   = (unsigned short*)(ws + 17301504);    //    131,072 B
  unsigned short* qs    = (unsigned short*)(ws + 17432576);    // 16,777,216 B
  unsigned short* ksb   = (unsigned short*)(ws + 34209792);    // 16,777,216 B
  unsigned short* vsb   = (unsigned short*)(ws + 50987008);    // 16,777,216 B
  unsigned short* gateb = (unsigned short*)(ws + 67764224);    // 16,777,216 B
  unsigned short* nbb   = (unsigned short*)(ws + 84541440);    //  1,048,576 B
  unsigned short* wag   = xb;  // alias: xb dead after k_gemm0

  k_convert<<<dim3(9024), dim3(256), 0, stream>>>(x, wqkv, wgate, wo, nb, xb, wallb, wob, nbb);
  k_gemm0<<<dim3(1024), dim3(512), 0, stream>>>(xb, wallb, qs, ksb, vsb, gateb, gbias);
  k_attn<<<dim3(128, 8), dim3(512), 0, stream>>>(qs, ksb, vsb, gateb, mask, nbb, wag);
  k_gemm1<<<dim3(256, 2), dim3(256), 0, stream>>>(wag, wob, outp, bo);
}

// Round 27
// 115.587 us; speedup vs baseline: 1.0186x; 1.0186x over previous
//
#include <hip/hip_runtime.h>
#include <stdint.h>

#define B2 128
#define NSEQ 256
#define DIM 256
#define NH 8
#define CH 32

typedef __attribute__((ext_vector_type(8))) __bf16 bf16x8;
typedef __attribute__((ext_vector_type(8))) unsigned short u16x8;
typedef __attribute__((ext_vector_type(4))) unsigned short u16x4;
typedef __attribute__((ext_vector_type(4))) unsigned int u32x4;
typedef __attribute__((ext_vector_type(4))) float f32x4;

__device__ __forceinline__ unsigned short f2bf(float f) {
  unsigned int u = __builtin_bit_cast(unsigned int, f);
  u += 0x7FFFu + ((u >> 16) & 1u);
  return (unsigned short)(u >> 16);
}
__device__ __forceinline__ float bf2f(unsigned short h) {
  unsigned int u = ((unsigned int)h) << 16;
  return __builtin_bit_cast(float, u);
}
__device__ __forceinline__ bf16x8 as_bf(u16x8 v) { return __builtin_bit_cast(bf16x8, v); }

__device__ __forceinline__ void gload16(void* lds, const void* g) {
  __builtin_amdgcn_global_load_lds(
      (__attribute__((address_space(1))) void*)(g),
      (__attribute__((address_space(3))) void*)(lds), 16, 0, 0);
}

// ---------------- K0: fp32 -> bf16 conversion (x + weights + nb) ----------------
__global__ void k_convert(const float* __restrict__ x, const float* __restrict__ wqkv,
                          const float* __restrict__ wgate, const float* __restrict__ wo,
                          const float* __restrict__ nb,
                          unsigned short* __restrict__ xb, unsigned short* __restrict__ wallb,
                          unsigned short* __restrict__ wob, unsigned short* __restrict__ nbb) {
  const int NX = 8388608, NWALL = 262144, NWO = 65536, NNB = 524288;
  int i = blockIdx.x * blockDim.x + threadIdx.x;
  int total4 = (NX + NWALL + NWO + NNB) >> 2;
  if (i >= total4) return;
  int e = i << 2;
  float4 v;
  unsigned short* dst;
  if (e < NX) {
    v = *reinterpret_cast<const float4*>(x + e);
    dst = xb + e;
  } else if (e < NX + NWALL) {
    int o = e - NX;
    v = (o < 196608) ? *reinterpret_cast<const float4*>(wqkv + o)
                     : *reinterpret_cast<const float4*>(wgate + (o - 196608));
    dst = wallb + o;
  } else if (e < NX + NWALL + NWO) {
    int o = e - NX - NWALL;
    v = *reinterpret_cast<const float4*>(wo + o);
    dst = wob + o;
  } else {
    int o = e - NX - NWALL - NWO;
    v = *reinterpret_cast<const float4*>(nb + o);
    dst = nbb + o;
  }
  u16x4 r;
  r[0] = f2bf(v.x); r[1] = f2bf(v.y); r[2] = f2bf(v.z); r[3] = f2bf(v.w);
  *reinterpret_cast<u16x4*>(dst) = r;
}

// ---------------- K1: QKV+gate GEMM, BM=128 BN=256, 512 threads (2x4 waves) ----------------
// 1D grid + chunked XCD swizzle (WIN: FETCH 16.5->12.3MB, 54.4->50.3us):
// orig=(bid&7)*128+(bid>>3) -> each XCD handles its 32 m-tiles with the 4
// n-variants consecutively (A-tile L2-hot on reuse). Row-pair LDS (0 conflicts),
// double-buffered single-barrier loop, transpose epilogue with 16B stores.
__launch_bounds__(512, 3)
__global__ void k_gemm0(const unsigned short* __restrict__ Ab, const unsigned short* __restrict__ Bw,
                        unsigned short* __restrict__ qs, unsigned short* __restrict__ ksb,
                        unsigned short* __restrict__ vsb, unsigned short* __restrict__ gateb,
                        const float* __restrict__ gbias) {
  __shared__ __attribute__((aligned(16))) char smem[49152];  // As 2x8KB | Bs 2x16KB; epilogue overlay
  const int tid = threadIdx.x, lane = tid & 63, w = tid >> 6;
  const int wr = w >> 2, wc = w & 3;
  const int l15 = lane & 15, hi = lane >> 4;
  const int bid = blockIdx.x;
  const int orig = (bid & 7) * 128 + (bid >> 3);  // bijective: 1024 % 8 == 0
  const int m0 = (orig >> 2) * 128;
  const int which = orig & 3;
  const int n0 = which * 256;

  auto stageA = [&](int buf, int k0) {
    char* sbuf = buf ? smem + 8192 : smem;
    int i = tid;                      // chunk i covers LDS byte i*16
    int rp = i >> 3, sp = i & 7;
    int sl = sp ^ (rp & 7);
    int row = 2 * rp + (sl >> 2), s3 = sl & 3;
    const unsigned short* g = Ab + (size_t)(m0 + row) * 256 + k0 + s3 * 8;
    gload16(sbuf + w * 1024, g);
  };
  auto stageB = [&](int buf, int k0) {
    char* sbuf = buf ? smem + 32768 : smem + 16384;
#pragma unroll
    for (int q2 = 0; q2 < 2; ++q2) {
      int i = q2 * 512 + tid;
      int rp = i >> 3, sp = i & 7;
      int sl = sp ^ (rp & 7);
      int row = 2 * rp + (sl >> 2), s3 = sl & 3;
      const unsigned short* g = Bw + (size_t)(n0 + row) * 256 + k0 + s3 * 8;
      gload16(sbuf + q2 * 8192 + w * 1024, g);
    }
  };

  f32x4 acc[4][4];
#pragma unroll
  for (int i = 0; i < 4; ++i) {
#pragma unroll
    for (int j = 0; j < 4; ++j) acc[i][j] = (f32x4){0.f, 0.f, 0.f, 0.f};
  }

  stageA(0, 0);
  stageB(0, 0);

#pragma unroll
  for (int kt = 0; kt < 8; ++kt) {
    const int cur = kt & 1;
    asm volatile("s_waitcnt vmcnt(0)" ::: "memory");
    __builtin_amdgcn_sched_barrier(0);
    __builtin_amdgcn_s_barrier();
    __builtin_amdgcn_sched_barrier(0);
    if (kt < 7) {
      stageA(cur ^ 1, (kt + 1) * 32);
      stageB(cur ^ 1, (kt + 1) * 32);
    }
    {
      const char* Acur = cur ? smem + 8192 : smem;
      const char* Bcur = cur ? smem + 32768 : smem + 16384;
      bf16x8 af[4], bfv[4];
#pragma unroll
      for (int fr = 0; fr < 4; ++fr) {
        int ra = wr * 64 + fr * 16 + l15;
        int rp = ra >> 1;
        int sl = ((ra & 1) << 2) | hi;
        int off = rp * 128 + (sl ^ (rp & 7)) * 16;
        af[fr] = *reinterpret_cast<const bf16x8*>(Acur + off);
      }
#pragma unroll
      for (int fc = 0; fc < 4; ++fc) {
        int rb = wc * 64 + fc * 16 + l15;
        int rp = rb >> 1;
        int sl = ((rb & 1) << 2) | hi;
        int off = rp * 128 + (sl ^ (rp & 7)) * 16;
        bfv[fc] = *reinterpret_cast<const bf16x8*>(Bcur + off);
      }
#pragma unroll
      for (int fr = 0; fr < 4; ++fr) {
#pragma unroll
        for (int fc = 0; fc < 4; ++fc)
          acc[fr][fc] = __builtin_amdgcn_mfma_f32_16x16x32_bf16(af[fr], bfv[fc], acc[fr][fc], 0, 0, 0);
      }
    }
  }

  // ---- epilogue: transpose through LDS, coalesced 16B stores ----
  unsigned short* ep = reinterpret_cast<unsigned short*>(smem);  // [64][264] bf16
  float gb4[4];
  if (which == 3) {
#pragma unroll
    for (int fc = 0; fc < 4; ++fc) gb4[fc] = gbias[wc * 64 + fc * 16 + l15];
  }
  unsigned short* dstbuf = (which == 0) ? qs : (which == 1) ? ksb : (which == 2) ? vsb : gateb;
#pragma unroll
  for (int half = 0; half < 2; ++half) {
    __syncthreads();  // prior smem readers (K-loop / prev half) done
    if (wr == half) {
#pragma unroll
      for (int fr = 0; fr < 4; ++fr) {
#pragma unroll
        for (int fc = 0; fc < 4; ++fc) {
          int col = wc * 64 + fc * 16 + l15;
#pragma unroll
          for (int i = 0; i < 4; ++i) {
            float v = acc[fr][fc][i];
            if (which == 0) v *= 0.17677669529663687f;  // C^-0.5
            if (which == 3) v = 1.0f / (1.0f + __expf(-(v + gb4[fc])));
            ep[(fr * 16 + (hi << 2) + i) * 264 + col] = f2bf(v);
          }
        }
      }
    }
    __syncthreads();
    const int row = tid >> 3, hh = tid & 7;
    const int mrow2 = m0 + half * 64 + row;
    const int b = mrow2 >> 8, n = mrow2 & 255;
    unsigned short* dst = dstbuf + ((size_t)(b * 8 + hh) * 256 + n) * 32;
    const unsigned short* src = ep + row * 264 + hh * 32;
#pragma unroll
    for (int q4 = 0; q4 < 4; ++q4)
      *reinterpret_cast<u16x8*>(dst + q4 * 8) = *reinterpret_cast<const u16x8*>(src + q4 * 8);
  }
}

// ---------------- K3: output GEMM ----------------
__launch_bounds__(256, 4)
__global__ void k_gemm1(const unsigned short* __restrict__ Ab, const unsigned short* __restrict__ Bw,
                        float* __restrict__ outp, const float* __restrict__ bo) {
  __shared__ __attribute__((aligned(16))) char As[2][8192];
  __shared__ __attribute__((aligned(16))) char Bs[2][8192];
  const int tid = threadIdx.x, lane = tid & 63, w = tid >> 6;
  const int wr = w >> 1, wc = w & 1;
  const int l15 = lane & 15, hi = lane >> 4;
  const int m0 = blockIdx.x * 128, n0 = blockIdx.y * 128;

  auto stage_pair = [&](char* sbuf, const unsigned short* gsrc, int row0, int k0) {
#pragma unroll
    for (int q2 = 0; q2 < 2; ++q2) {
      int i = q2 * 256 + tid;
      int rp = i >> 3, sp = i & 7;
      int sl = sp ^ (rp & 7);
      int row = 2 * rp + (sl >> 2), s3 = sl & 3;
      const unsigned short* g = gsrc + (size_t)(row0 + row) * 256 + k0 + s3 * 8;
      gload16(sbuf + q2 * 4096 + w * 1024, g);
    }
  };

  f32x4 acc[4][4];
#pragma unroll
  for (int i = 0; i < 4; ++i) {
#pragma unroll
    for (int j = 0; j < 4; ++j) acc[i][j] = (f32x4){0.f, 0.f, 0.f, 0.f};
  }

  stage_pair(As[0], Ab, m0, 0);
  stage_pair(Bs[0], Bw, n0, 0);

#pragma unroll
  for (int kt = 0; kt < 8; ++kt) {
    const int cur = kt & 1;
    asm volatile("s_waitcnt vmcnt(0)" ::: "memory");
    __builtin_amdgcn_sched_barrier(0);
    __builtin_amdgcn_s_barrier();
    __builtin_amdgcn_sched_barrier(0);
    if (kt < 7) {
      stage_pair(As[cur ^ 1], Ab, m0, (kt + 1) * 32);
      stage_pair(Bs[cur ^ 1], Bw, n0, (kt + 1) * 32);
    }
    {
      bf16x8 af[4], bfv[4];
#pragma unroll
      for (int fr = 0; fr < 4; ++fr) {
        int ra = wr * 64 + fr * 16 + l15;
        int rp = ra >> 1;
        int sl = ((ra & 1) << 2) | hi;
        int off = rp * 128 + (sl ^ (rp & 7)) * 16;
        af[fr] = *reinterpret_cast<const bf16x8*>(As[cur] + off);
      }
#pragma unroll
      for (int fc = 0; fc < 4; ++fc) {
        int rb = wc * 64 + fc * 16 + l15;
        int rp = rb >> 1;
        int sl = ((rb & 1) << 2) | hi;
        int off = rp * 128 + (sl ^ (rp & 7)) * 16;
        bfv[fc] = *reinterpret_cast<const bf16x8*>(Bs[cur] + off);
      }
#pragma unroll
      for (int fr = 0; fr < 4; ++fr) {
#pragma unroll
        for (int fc = 0; fc < 4; ++fc)
          acc[fr][fc] = __builtin_amdgcn_mfma_f32_16x16x32_bf16(af[fr], bfv[fc], acc[fr][fc], 0, 0, 0);
      }
    }
  }

#pragma unroll
  for (int fr = 0; fr < 4; ++fr) {
    int mrow = m0 + wr * 64 + fr * 16 + (hi << 2);
#pragma unroll
    for (int fc = 0; fc < 4; ++fc) {
      int e = n0 + wc * 64 + fc * 16 + l15;
      float bb = bo[e];
#pragma unroll
      for (int i = 0; i < 4; ++i)
        outp[(size_t)(mrow + i) * 256 + e] = acc[fr][fc][i] + bb;
    }
  }
}

// ---------------- K2: attention per (b2, head), 512 threads = 8 waves ----------------
// (byte-identical to Round 25 — the hoist variant halved occupancy for no gain)
__launch_bounds__(512, 2)
__global__ void k_attn(const unsigned short* __restrict__ qs, const unsigned short* __restrict__ ksb,
                       const unsigned short* __restrict__ vsb, const unsigned short* __restrict__ gateb,
                       const float* __restrict__ mask, const unsigned short* __restrict__ nbb,
                       unsigned short* __restrict__ wag) {
  __shared__ __attribute__((aligned(16))) unsigned short vt[32][264];     // V^T [c][key]
  __shared__ __attribute__((aligned(16))) unsigned short pch[8][16][72];  // per-wave P chunk
  __shared__ __attribute__((aligned(16))) unsigned short Kl[16][64][8];   // K frags, lane-linear
  __shared__ __attribute__((aligned(16))) float mb[256];
  __shared__ float invl[8][16];
  const int tid = threadIdx.x, lane = tid & 63, w = tid >> 6;
  const int l15 = lane & 15, hi = lane >> 4;
  const int b = blockIdx.x, h = blockIdx.y;
  const size_t bh = (size_t)(b * 8 + h);
  const unsigned short* kbase = ksb + bh * 8192;
  const unsigned short* vbase = vsb + bh * 8192;
  const unsigned short* qbase = qs + bh * 8192;
  const unsigned short* nbh = nbb + (size_t)h * 65536;

  if (tid < 256) {
    mb[tid] = 1e9f * (mask[b * 256 + tid] - 1.0f);
    const unsigned short* vrow = vbase + tid * 32;
#pragma unroll
    for (int c0 = 0; c0 < 32; c0 += 8) {
      u16x8 vv = *reinterpret_cast<const u16x8*>(vrow + c0);
#pragma unroll
      for (int j = 0; j < 8; ++j) vt[c0 + j][tid] = vv[j];
    }
  } else {
    const int key = tid - 256;
    const unsigned short* krow = kbase + key * 32;
#pragma unroll
    for (int c8 = 0; c8 < 4; ++c8)
      *reinterpret_cast<u16x8*>(&Kl[key >> 4][c8 * 16 + (key & 15)][0]) =
          *reinterpret_cast<const u16x8*>(krow + c8 * 8);
  }
  __syncthreads();

  const f32x4 zero = {0.f, 0.f, 0.f, 0.f};
#pragma unroll 1
  for (int fr = 0; fr < 2; ++fr) {
    const int q0 = w * 32 + fr * 16;
    u16x8 qf = *reinterpret_cast<const u16x8*>(qbase + (q0 + l15) * 32 + hi * 8);

    // nb prefetch (bf16, 32 VGPRs) — issued before the MFMA cluster
    const unsigned short* nbq = nbh + (size_t)(q0 + l15) * 256;
    u16x4 nbv[16];
#pragma unroll
    for (int kt = 0; kt < 16; ++kt)
      nbv[kt] = *reinterpret_cast<const u16x4*>(nbq + kt * 16 + hi * 4);

    f32x4 sacc[16];
    __builtin_amdgcn_s_setprio(1);
#pragma unroll
    for (int kt = 0; kt < 16; ++kt) {
      bf16x8 kf = *reinterpret_cast<const bf16x8*>(&Kl[kt][lane][0]);
      sacc[kt] = __builtin_amdgcn_mfma_f32_16x16x32_bf16(kf, as_bf(qf), zero, 0, 0, 0);
    }
    __builtin_amdgcn_s_setprio(0);

#pragma unroll
    for (int kt = 0; kt < 16; ++kt) {
      float4 mb4 = *reinterpret_cast<const float4*>(&mb[kt * 16 + hi * 4]);
      sacc[kt][0] += mb4.x + bf2f(nbv[kt][0]);
      sacc[kt][1] += mb4.y + bf2f(nbv[kt][1]);
      sacc[kt][2] += mb4.z + bf2f(nbv[kt][2]);
      sacc[kt][3] += mb4.w + bf2f(nbv[kt][3]);
    }
    float mx = -3.0e38f;
#pragma unroll
    for (int kt = 0; kt < 16; ++kt) {
#pragma unroll
      for (int i = 0; i < 4; ++i) mx = fmaxf(mx, sacc[kt][i]);
    }
    mx = fmaxf(mx, __shfl_xor(mx, 16));
    mx = fmaxf(mx, __shfl_xor(mx, 32));

    float sum = 0.f;
    f32x4 wacc[2];
    wacc[0] = zero; wacc[1] = zero;
#pragma unroll
    for (int c = 0; c < 4; ++c) {
#pragma unroll
      for (int ktl = 0; ktl < 4; ++ktl) {
        const int kt = c * 4 + ktl;
        u16x4 pv;
#pragma unroll
        for (int i = 0; i < 4; ++i) {
          float p = __expf(sacc[kt][i] - mx);
          sum += p;
          pv[i] = f2bf(p);  // unnormalized; inv folded into epilogue
        }
        *reinterpret_cast<u16x4*>(&pch[w][l15][ktl * 16 + hi * 4]) = pv;
      }
      asm volatile("" ::: "memory");  // compile-time order: pch writes before pa reads
      __builtin_amdgcn_s_setprio(1);
#pragma unroll
      for (int ks2 = 0; ks2 < 2; ++ks2) {
        bf16x8 pa = *reinterpret_cast<const bf16x8*>(&pch[w][l15][ks2 * 32 + hi * 8]);
#pragma unroll
        for (int ct = 0; ct < 2; ++ct) {
          bf16x8 vb = *reinterpret_cast<const bf16x8*>(&vt[ct * 16 + l15][c * 64 + ks2 * 32 + hi * 8]);
          wacc[ct] = __builtin_amdgcn_mfma_f32_16x16x32_bf16(pa, vb, wacc[ct], 0, 0, 0);
        }
      }
      __builtin_amdgcn_s_setprio(0);
    }
    sum += __shfl_xor(sum, 16);
    sum += __shfl_xor(sum, 32);
    const float inv = 1.0f / sum;
    if (hi == 0) invl[w][l15] = inv;

    // Epilogue: transpose wacc through LDS (reuse pch[w] as [16][36] f32)
    asm volatile("" ::: "memory");  // order: pa reads before et overwrites
    float* et = reinterpret_cast<float*>(&pch[w][0][0]);
#pragma unroll
    for (int ct = 0; ct < 2; ++ct) {
#pragma unroll
      for (int i = 0; i < 4; ++i)
        et[(hi * 4 + i) * 36 + ct * 16 + l15] = wacc[ct][i];
    }
    asm volatile("" ::: "memory");  // order: et writes before et reads
    const int eq = lane >> 2, eh = lane & 3;
    float4 v0 = *reinterpret_cast<const float4*>(&et[eq * 36 + eh * 8]);
    float4 v1 = *reinterpret_cast<const float4*>(&et[eq * 36 + eh * 8 + 4]);
    const float iv = invl[w][eq];
    const int qrow = q0 + eq;
    u16x8 g = *reinterpret_cast<const u16x8*>(gateb + bh * 8192 + qrow * 32 + eh * 8);
    u16x8 ov;
    ov[0] = f2bf(bf2f(g[0]) * v0.x * iv);
    ov[1] = f2bf(bf2f(g[1]) * v0.y * iv);
    ov[2] = f2bf(bf2f(g[2]) * v0.z * iv);
    ov[3] = f2bf(bf2f(g[3]) * v0.w * iv);
    ov[4] = f2bf(bf2f(g[4]) * v1.x * iv);
    ov[5] = f2bf(bf2f(g[5]) * v1.y * iv);
    ov[6] = f2bf(bf2f(g[6]) * v1.z * iv);
    ov[7] = f2bf(bf2f(g[7]) * v1.w * iv);
    *reinterpret_cast<u16x8*>(wag + ((size_t)(b * 256 + qrow)) * 256 + h * 32 + eh * 8) = ov;
    asm volatile("" ::: "memory");  // order: et reads before next fr's pch writes
  }
}

extern "C" void kernel_launch(void* const* d_in, const int* in_sizes, int n_in,
                              void* d_out, int out_size, void* d_ws, size_t ws_size,
                              hipStream_t stream) {
  const float* x     = (const float*)d_in[0];
  const float* mask  = (const float*)d_in[1];
  const float* nb    = (const float*)d_in[2];
  const float* wqkv  = (const float*)d_in[3];
  const float* wgate = (const float*)d_in[4];
  const float* gbias = (const float*)d_in[5];
  const float* wo    = (const float*)d_in[6];
  const float* bo    = (const float*)d_in[7];
  float* outp = (float*)d_out;

  char* ws = (char*)d_ws;
  unsigned short* xb    = (unsigned short*)(ws);               // 16,777,216 B
  unsigned short* wallb = (unsigned short*)(ws + 16777216);    //    524,288 B
  unsigned short* wob   = (unsigned short*)(ws + 17301504);    //    131,072 B
  unsigned short* qs    = (unsigned short*)(ws + 17432576);    // 16,777,216 B
  unsigned short* ksb   = (unsigned short*)(ws + 34209792);    // 16,777,216 B
  unsigned short* vsb   = (unsigned short*)(ws + 50987008);    // 16,777,216 B
  unsigned short* gateb = (unsigned short*)(ws + 67764224);    // 16,777,216 B
  unsigned short* nbb   = (unsigned short*)(ws + 84541440);    //  1,048,576 B
  unsigned short* wag   = xb;  // alias: xb dead after k_gemm0

  k_convert<<<dim3(9024), dim3(256), 0, stream>>>(x, wqkv, wgate, wo, nb, xb, wallb, wob, nbb);
  k_gemm0<<<dim3(1024), dim3(512), 0, stream>>>(xb, wallb, qs, ksb, vsb, gateb, gbias);
  k_attn<<<dim3(128, 8), dim3(512), 0, stream>>>(qs, ksb, vsb, gateb, mask, nbb, wag);
  k_gemm1<<<dim3(256, 2), dim3(256), 0, stream>>>(wag, wob, outp, bo);
}

// Round 28
// 114.404 us; speedup vs baseline: 1.0292x; 1.0103x over previous
//
#include <hip/hip_runtime.h>
#include <stdint.h>

#define B2 128
#define NSEQ 256
#define DIM 256
#define NH 8
#define CH 32

typedef __attribute__((ext_vector_type(8))) __bf16 bf16x8;
typedef __attribute__((ext_vector_type(8))) unsigned short u16x8;
typedef __attribute__((ext_vector_type(4))) unsigned short u16x4;
typedef __attribute__((ext_vector_type(4))) unsigned int u32x4;
typedef __attribute__((ext_vector_type(4))) float f32x4;

__device__ __forceinline__ unsigned short f2bf(float f) {
  unsigned int u = __builtin_bit_cast(unsigned int, f);
  u += 0x7FFFu + ((u >> 16) & 1u);
  return (unsigned short)(u >> 16);
}
__device__ __forceinline__ float bf2f(unsigned short h) {
  unsigned int u = ((unsigned int)h) << 16;
  return __builtin_bit_cast(float, u);
}
__device__ __forceinline__ bf16x8 as_bf(u16x8 v) { return __builtin_bit_cast(bf16x8, v); }
__device__ __forceinline__ unsigned int cvtpk(float lo, float hi) {
  unsigned int r;
  asm("v_cvt_pk_bf16_f32 %0, %1, %2" : "=v"(r) : "v"(lo), "v"(hi));
  return r;
}

__device__ __forceinline__ void gload16(void* lds, const void* g) {
  __builtin_amdgcn_global_load_lds(
      (__attribute__((address_space(1))) void*)(g),
      (__attribute__((address_space(3))) void*)(lds), 16, 0, 0);
}

// ---------------- K0: fp32 -> bf16 conversion (x + weights + nb) ----------------
__global__ void k_convert(const float* __restrict__ x, const float* __restrict__ wqkv,
                          const float* __restrict__ wgate, const float* __restrict__ wo,
                          const float* __restrict__ nb,
                          unsigned short* __restrict__ xb, unsigned short* __restrict__ wallb,
                          unsigned short* __restrict__ wob, unsigned short* __restrict__ nbb) {
  const int NX = 8388608, NWALL = 262144, NWO = 65536, NNB = 524288;
  int i = blockIdx.x * blockDim.x + threadIdx.x;
  int total4 = (NX + NWALL + NWO + NNB) >> 2;
  if (i >= total4) return;
  int e = i << 2;
  float4 v;
  unsigned short* dst;
  if (e < NX) {
    v = *reinterpret_cast<const float4*>(x + e);
    dst = xb + e;
  } else if (e < NX + NWALL) {
    int o = e - NX;
    v = (o < 196608) ? *reinterpret_cast<const float4*>(wqkv + o)
                     : *reinterpret_cast<const float4*>(wgate + (o - 196608));
    dst = wallb + o;
  } else if (e < NX + NWALL + NWO) {
    int o = e - NX - NWALL;
    v = *reinterpret_cast<const float4*>(wo + o);
    dst = wob + o;
  } else {
    int o = e - NX - NWALL - NWO;
    v = *reinterpret_cast<const float4*>(nb + o);
    dst = nbb + o;
  }
  u16x4 r;
  r[0] = f2bf(v.x); r[1] = f2bf(v.y); r[2] = f2bf(v.z); r[3] = f2bf(v.w);
  *reinterpret_cast<u16x4*>(dst) = r;
}

// ---------------- K1: QKV+gate GEMM, BM=128 BN=256, 512 threads (2x4 waves) ----------------
// 1D grid + chunked XCD swizzle: orig=(bid&7)*128+(bid>>3). Row-pair LDS
// (0 conflicts), double-buffered single-barrier loop, transpose epilogue.
__launch_bounds__(512, 3)
__global__ void k_gemm0(const unsigned short* __restrict__ Ab, const unsigned short* __restrict__ Bw,
                        unsigned short* __restrict__ qs, unsigned short* __restrict__ ksb,
                        unsigned short* __restrict__ vsb, unsigned short* __restrict__ gateb,
                        const float* __restrict__ gbias) {
  __shared__ __attribute__((aligned(16))) char smem[49152];  // As 2x8KB | Bs 2x16KB; epilogue overlay
  const int tid = threadIdx.x, lane = tid & 63, w = tid >> 6;
  const int wr = w >> 2, wc = w & 3;
  const int l15 = lane & 15, hi = lane >> 4;
  const int bid = blockIdx.x;
  const int orig = (bid & 7) * 128 + (bid >> 3);  // bijective: 1024 % 8 == 0
  const int m0 = (orig >> 2) * 128;
  const int which = orig & 3;
  const int n0 = which * 256;

  auto stageA = [&](int buf, int k0) {
    char* sbuf = buf ? smem + 8192 : smem;
    int i = tid;                      // chunk i covers LDS byte i*16
    int rp = i >> 3, sp = i & 7;
    int sl = sp ^ (rp & 7);
    int row = 2 * rp + (sl >> 2), s3 = sl & 3;
    const unsigned short* g = Ab + (size_t)(m0 + row) * 256 + k0 + s3 * 8;
    gload16(sbuf + w * 1024, g);
  };
  auto stageB = [&](int buf, int k0) {
    char* sbuf = buf ? smem + 32768 : smem + 16384;
#pragma unroll
    for (int q2 = 0; q2 < 2; ++q2) {
      int i = q2 * 512 + tid;
      int rp = i >> 3, sp = i & 7;
      int sl = sp ^ (rp & 7);
      int row = 2 * rp + (sl >> 2), s3 = sl & 3;
      const unsigned short* g = Bw + (size_t)(n0 + row) * 256 + k0 + s3 * 8;
      gload16(sbuf + q2 * 8192 + w * 1024, g);
    }
  };

  f32x4 acc[4][4];
#pragma unroll
  for (int i = 0; i < 4; ++i) {
#pragma unroll
    for (int j = 0; j < 4; ++j) acc[i][j] = (f32x4){0.f, 0.f, 0.f, 0.f};
  }

  stageA(0, 0);
  stageB(0, 0);

#pragma unroll
  for (int kt = 0; kt < 8; ++kt) {
    const int cur = kt & 1;
    asm volatile("s_waitcnt vmcnt(0)" ::: "memory");
    __builtin_amdgcn_sched_barrier(0);
    __builtin_amdgcn_s_barrier();
    __builtin_amdgcn_sched_barrier(0);
    if (kt < 7) {
      stageA(cur ^ 1, (kt + 1) * 32);
      stageB(cur ^ 1, (kt + 1) * 32);
    }
    {
      const char* Acur = cur ? smem + 8192 : smem;
      const char* Bcur = cur ? smem + 32768 : smem + 16384;
      bf16x8 af[4], bfv[4];
#pragma unroll
      for (int fr = 0; fr < 4; ++fr) {
        int ra = wr * 64 + fr * 16 + l15;
        int rp = ra >> 1;
        int sl = ((ra & 1) << 2) | hi;
        int off = rp * 128 + (sl ^ (rp & 7)) * 16;
        af[fr] = *reinterpret_cast<const bf16x8*>(Acur + off);
      }
#pragma unroll
      for (int fc = 0; fc < 4; ++fc) {
        int rb = wc * 64 + fc * 16 + l15;
        int rp = rb >> 1;
        int sl = ((rb & 1) << 2) | hi;
        int off = rp * 128 + (sl ^ (rp & 7)) * 16;
        bfv[fc] = *reinterpret_cast<const bf16x8*>(Bcur + off);
      }
#pragma unroll
      for (int fr = 0; fr < 4; ++fr) {
#pragma unroll
        for (int fc = 0; fc < 4; ++fc)
          acc[fr][fc] = __builtin_amdgcn_mfma_f32_16x16x32_bf16(af[fr], bfv[fc], acc[fr][fc], 0, 0, 0);
      }
    }
  }

  // ---- epilogue: transpose through LDS, coalesced 16B stores ----
  unsigned short* ep = reinterpret_cast<unsigned short*>(smem);  // [64][264] bf16
  float gb4[4];
  if (which == 3) {
#pragma unroll
    for (int fc = 0; fc < 4; ++fc) gb4[fc] = gbias[wc * 64 + fc * 16 + l15];
  }
  unsigned short* dstbuf = (which == 0) ? qs : (which == 1) ? ksb : (which == 2) ? vsb : gateb;
#pragma unroll
  for (int half = 0; half < 2; ++half) {
    __syncthreads();  // prior smem readers (K-loop / prev half) done
    if (wr == half) {
#pragma unroll
      for (int fr = 0; fr < 4; ++fr) {
#pragma unroll
        for (int fc = 0; fc < 4; ++fc) {
          int col = wc * 64 + fc * 16 + l15;
#pragma unroll
          for (int i = 0; i < 4; ++i) {
            float v = acc[fr][fc][i];
            if (which == 0) v *= 0.17677669529663687f;  // C^-0.5
            if (which == 3) v = 1.0f / (1.0f + __expf(-(v + gb4[fc])));
            ep[(fr * 16 + (hi << 2) + i) * 264 + col] = f2bf(v);
          }
        }
      }
    }
    __syncthreads();
    const int row = tid >> 3, hh = tid & 7;
    const int mrow2 = m0 + half * 64 + row;
    const int b = mrow2 >> 8, n = mrow2 & 255;
    unsigned short* dst = dstbuf + ((size_t)(b * 8 + hh) * 256 + n) * 32;
    const unsigned short* src = ep + row * 264 + hh * 32;
#pragma unroll
    for (int q4 = 0; q4 < 4; ++q4)
      *reinterpret_cast<u16x8*>(dst + q4 * 8) = *reinterpret_cast<const u16x8*>(src + q4 * 8);
  }
}

// ---------------- K3: output GEMM ----------------
__launch_bounds__(256, 4)
__global__ void k_gemm1(const unsigned short* __restrict__ Ab, const unsigned short* __restrict__ Bw,
                        float* __restrict__ outp, const float* __restrict__ bo) {
  __shared__ __attribute__((aligned(16))) char As[2][8192];
  __shared__ __attribute__((aligned(16))) char Bs[2][8192];
  const int tid = threadIdx.x, lane = tid & 63, w = tid >> 6;
  const int wr = w >> 1, wc = w & 1;
  const int l15 = lane & 15, hi = lane >> 4;
  const int m0 = blockIdx.x * 128, n0 = blockIdx.y * 128;

  auto stage_pair = [&](char* sbuf, const unsigned short* gsrc, int row0, int k0) {
#pragma unroll
    for (int q2 = 0; q2 < 2; ++q2) {
      int i = q2 * 256 + tid;
      int rp = i >> 3, sp = i & 7;
      int sl = sp ^ (rp & 7);
      int row = 2 * rp + (sl >> 2), s3 = sl & 3;
      const unsigned short* g = gsrc + (size_t)(row0 + row) * 256 + k0 + s3 * 8;
      gload16(sbuf + q2 * 4096 + w * 1024, g);
    }
  };

  f32x4 acc[4][4];
#pragma unroll
  for (int i = 0; i < 4; ++i) {
#pragma unroll
    for (int j = 0; j < 4; ++j) acc[i][j] = (f32x4){0.f, 0.f, 0.f, 0.f};
  }

  stage_pair(As[0], Ab, m0, 0);
  stage_pair(Bs[0], Bw, n0, 0);

#pragma unroll
  for (int kt = 0; kt < 8; ++kt) {
    const int cur = kt & 1;
    asm volatile("s_waitcnt vmcnt(0)" ::: "memory");
    __builtin_amdgcn_sched_barrier(0);
    __builtin_amdgcn_s_barrier();
    __builtin_amdgcn_sched_barrier(0);
    if (kt < 7) {
      stage_pair(As[cur ^ 1], Ab, m0, (kt + 1) * 32);
      stage_pair(Bs[cur ^ 1], Bw, n0, (kt + 1) * 32);
    }
    {
      bf16x8 af[4], bfv[4];
#pragma unroll
      for (int fr = 0; fr < 4; ++fr) {
        int ra = wr * 64 + fr * 16 + l15;
        int rp = ra >> 1;
        int sl = ((ra & 1) << 2) | hi;
        int off = rp * 128 + (sl ^ (rp & 7)) * 16;
        af[fr] = *reinterpret_cast<const bf16x8*>(As[cur] + off);
      }
#pragma unroll
      for (int fc = 0; fc < 4; ++fc) {
        int rb = wc * 64 + fc * 16 + l15;
        int rp = rb >> 1;
        int sl = ((rb & 1) << 2) | hi;
        int off = rp * 128 + (sl ^ (rp & 7)) * 16;
        bfv[fc] = *reinterpret_cast<const bf16x8*>(Bs[cur] + off);
      }
#pragma unroll
      for (int fr = 0; fr < 4; ++fr) {
#pragma unroll
        for (int fc = 0; fc < 4; ++fc)
          acc[fr][fc] = __builtin_amdgcn_mfma_f32_16x16x32_bf16(af[fr], bfv[fc], acc[fr][fc], 0, 0, 0);
      }
    }
  }

#pragma unroll
  for (int fr = 0; fr < 4; ++fr) {
    int mrow = m0 + wr * 64 + fr * 16 + (hi << 2);
#pragma unroll
    for (int fc = 0; fc < 4; ++fc) {
      int e = n0 + wc * 64 + fc * 16 + l15;
      float bb = bo[e];
#pragma unroll
      for (int i = 0; i < 4; ++i)
        outp[(size_t)(mrow + i) * 256 + e] = acc[fr][fc][i] + bb;
    }
  }
}

// ---------------- K2: attention per (b2, head), 512 threads = 8 waves ----------------
// VALU cut: P-store and epilogue use v_cvt_pk_bf16_f32 (1 op per bf16 pair)
// instead of 4-op hand-rolled f2bf; max-reduce via fmax triples (v_max3).
__launch_bounds__(512, 2)
__global__ void k_attn(const unsigned short* __restrict__ qs, const unsigned short* __restrict__ ksb,
                       const unsigned short* __restrict__ vsb, const unsigned short* __restrict__ gateb,
                       const float* __restrict__ mask, const unsigned short* __restrict__ nbb,
                       unsigned short* __restrict__ wag) {
  __shared__ __attribute__((aligned(16))) unsigned short vt[32][264];     // V^T [c][key]
  __shared__ __attribute__((aligned(16))) unsigned short pch[8][16][72];  // per-wave P chunk
  __shared__ __attribute__((aligned(16))) unsigned short Kl[16][64][8];   // K frags, lane-linear
  __shared__ __attribute__((aligned(16))) float mb[256];
  __shared__ float invl[8][16];
  const int tid = threadIdx.x, lane = tid & 63, w = tid >> 6;
  const int l15 = lane & 15, hi = lane >> 4;
  const int b = blockIdx.x, h = blockIdx.y;
  const size_t bh = (size_t)(b * 8 + h);
  const unsigned short* kbase = ksb + bh * 8192;
  const unsigned short* vbase = vsb + bh * 8192;
  const unsigned short* qbase = qs + bh * 8192;
  const unsigned short* nbh = nbb + (size_t)h * 65536;

  if (tid < 256) {
    mb[tid] = 1e9f * (mask[b * 256 + tid] - 1.0f);
    const unsigned short* vrow = vbase + tid * 32;
#pragma unroll
    for (int c0 = 0; c0 < 32; c0 += 8) {
      u16x8 vv = *reinterpret_cast<const u16x8*>(vrow + c0);
#pragma unroll
      for (int j = 0; j < 8; ++j) vt[c0 + j][tid] = vv[j];
    }
  } else {
    const int key = tid - 256;
    const unsigned short* krow = kbase + key * 32;
#pragma unroll
    for (int c8 = 0; c8 < 4; ++c8)
      *reinterpret_cast<u16x8*>(&Kl[key >> 4][c8 * 16 + (key & 15)][0]) =
          *reinterpret_cast<const u16x8*>(krow + c8 * 8);
  }
  __syncthreads();

  const f32x4 zero = {0.f, 0.f, 0.f, 0.f};
#pragma unroll 1
  for (int fr = 0; fr < 2; ++fr) {
    const int q0 = w * 32 + fr * 16;
    u16x8 qf = *reinterpret_cast<const u16x8*>(qbase + (q0 + l15) * 32 + hi * 8);

    // nb prefetch (bf16, 32 VGPRs) — issued before the MFMA cluster
    const unsigned short* nbq = nbh + (size_t)(q0 + l15) * 256;
    u16x4 nbv[16];
#pragma unroll
    for (int kt = 0; kt < 16; ++kt)
      nbv[kt] = *reinterpret_cast<const u16x4*>(nbq + kt * 16 + hi * 4);

    f32x4 sacc[16];
    __builtin_amdgcn_s_setprio(1);
#pragma unroll
    for (int kt = 0; kt < 16; ++kt) {
      bf16x8 kf = *reinterpret_cast<const bf16x8*>(&Kl[kt][lane][0]);
      sacc[kt] = __builtin_amdgcn_mfma_f32_16x16x32_bf16(kf, as_bf(qf), zero, 0, 0, 0);
    }
    __builtin_amdgcn_s_setprio(0);

#pragma unroll
    for (int kt = 0; kt < 16; ++kt) {
      float4 mb4 = *reinterpret_cast<const float4*>(&mb[kt * 16 + hi * 4]);
      sacc[kt][0] += mb4.x + bf2f(nbv[kt][0]);
      sacc[kt][1] += mb4.y + bf2f(nbv[kt][1]);
      sacc[kt][2] += mb4.z + bf2f(nbv[kt][2]);
      sacc[kt][3] += mb4.w + bf2f(nbv[kt][3]);
    }
    // max reduce via fmax triples (fuses to v_max3_f32)
    float m4[4];
#pragma unroll
    for (int i = 0; i < 4; ++i) {
      float a = fmaxf(fmaxf(sacc[0][i], sacc[1][i]), sacc[2][i]);
      float bb2 = fmaxf(fmaxf(sacc[3][i], sacc[4][i]), sacc[5][i]);
      float cc = fmaxf(fmaxf(sacc[6][i], sacc[7][i]), sacc[8][i]);
      float dd = fmaxf(fmaxf(sacc[9][i], sacc[10][i]), sacc[11][i]);
      float ee = fmaxf(fmaxf(sacc[12][i], sacc[13][i]), sacc[14][i]);
      float ff = fmaxf(sacc[15][i], fmaxf(a, bb2));
      m4[i] = fmaxf(fmaxf(cc, dd), fmaxf(ee, ff));
    }
    float mx = fmaxf(fmaxf(m4[0], m4[1]), fmaxf(m4[2], m4[3]));
    mx = fmaxf(mx, __shfl_xor(mx, 16));
    mx = fmaxf(mx, __shfl_xor(mx, 32));

    float sum = 0.f;
    f32x4 wacc[2];
    wacc[0] = zero; wacc[1] = zero;
#pragma unroll
    for (int c = 0; c < 4; ++c) {
#pragma unroll
      for (int ktl = 0; ktl < 4; ++ktl) {
        const int kt = c * 4 + ktl;
        float p0 = __expf(sacc[kt][0] - mx);
        float p1 = __expf(sacc[kt][1] - mx);
        float p2 = __expf(sacc[kt][2] - mx);
        float p3 = __expf(sacc[kt][3] - mx);
        sum += (p0 + p1) + (p2 + p3);
        uint2 pv;
        pv.x = cvtpk(p0, p1);  // unnormalized; inv folded into epilogue
        pv.y = cvtpk(p2, p3);
        *reinterpret_cast<uint2*>(&pch[w][l15][ktl * 16 + hi * 4]) = pv;
      }
      asm volatile("" ::: "memory");  // compile-time order: pch writes before pa reads
      __builtin_amdgcn_s_setprio(1);
#pragma unroll
      for (int ks2 = 0; ks2 < 2; ++ks2) {
        bf16x8 pa = *reinterpret_cast<const bf16x8*>(&pch[w][l15][ks2 * 32 + hi * 8]);
#pragma unroll
        for (int ct = 0; ct < 2; ++ct) {
          bf16x8 vb = *reinterpret_cast<const bf16x8*>(&vt[ct * 16 + l15][c * 64 + ks2 * 32 + hi * 8]);
          wacc[ct] = __builtin_amdgcn_mfma_f32_16x16x32_bf16(pa, vb, wacc[ct], 0, 0, 0);
        }
      }
      __builtin_amdgcn_s_setprio(0);
    }
    sum += __shfl_xor(sum, 16);
    sum += __shfl_xor(sum, 32);
    const float inv = 1.0f / sum;
    if (hi == 0) invl[w][l15] = inv;

    // Epilogue: transpose wacc through LDS (reuse pch[w] as [16][36] f32)
    asm volatile("" ::: "memory");  // order: pa reads before et overwrites
    float* et = reinterpret_cast<float*>(&pch[w][0][0]);
#pragma unroll
    for (int ct = 0; ct < 2; ++ct) {
#pragma unroll
      for (int i = 0; i < 4; ++i)
        et[(hi * 4 + i) * 36 + ct * 16 + l15] = wacc[ct][i];
    }
    asm volatile("" ::: "memory");  // order: et writes before et reads
    const int eq = lane >> 2, eh = lane & 3;
    float4 v0 = *reinterpret_cast<const float4*>(&et[eq * 36 + eh * 8]);
    float4 v1 = *reinterpret_cast<const float4*>(&et[eq * 36 + eh * 8 + 4]);
    const float iv = invl[w][eq];
    const int qrow = q0 + eq;
    u16x8 g = *reinterpret_cast<const u16x8*>(gateb + bh * 8192 + qrow * 32 + eh * 8);
    float o0 = bf2f(g[0]) * v0.x * iv;
    float o1 = bf2f(g[1]) * v0.y * iv;
    float o2 = bf2f(g[2]) * v0.z * iv;
    float o3 = bf2f(g[3]) * v0.w * iv;
    float o4 = bf2f(g[4]) * v1.x * iv;
    float o5 = bf2f(g[5]) * v1.y * iv;
    float o6 = bf2f(g[6]) * v1.z * iv;
    float o7 = bf2f(g[7]) * v1.w * iv;
    u32x4 ovu;
    ovu[0] = cvtpk(o0, o1);
    ovu[1] = cvtpk(o2, o3);
    ovu[2] = cvtpk(o4, o5);
    ovu[3] = cvtpk(o6, o7);
    *reinterpret_cast<u32x4*>(wag + ((size_t)(b * 256 + qrow)) * 256 + h * 32 + eh * 8) = ovu;
    asm volatile("" ::: "memory");  // order: et reads before next fr's pch writes
  }
}

extern "C" void kernel_launch(void* const* d_in, const int* in_sizes, int n_in,
                              void* d_out, int out_size, void* d_ws, size_t ws_size,
                              hipStream_t stream) {
  const float* x     = (const float*)d_in[0];
  const float* mask  = (const float*)d_in[1];
  const float* nb    = (const float*)d_in[2];
  const float* wqkv  = (const float*)d_in[3];
  const float* wgate = (const float*)d_in[4];
  const float* gbias = (const float*)d_in[5];
  const float* wo    = (const float*)d_in[6];
  const float* bo    = (const float*)d_in[7];
  float* outp = (float*)d_out;

  char* ws = (char*)d_ws;
  unsigned short* xb    = (unsigned short*)(ws);               // 16,777,216 B
  unsigned short* wallb = (unsigned short*)(ws + 16777216);    //    524,288 B
  unsigned short* wob   = (unsigned short*)(ws + 17301504);    //    131,072 B
  unsigned short* qs    = (unsigned short*)(ws + 17432576);    // 16,777,216 B
  unsigned short* ksb   = (unsigned short*)(ws + 34209792);    // 16,777,216 B
  unsigned short* vsb   = (unsigned short*)(ws + 50987008);    // 16,777,216 B
  unsigned short* gateb = (unsigned short*)(ws + 67764224);    // 16,777,216 B
  unsigned short* nbb   = (unsigned short*)(ws + 84541440);    //  1,048,576 B
  unsigned short* wag   = xb;  // alias: xb dead after k_gemm0

  k_convert<<<dim3(9024), dim3(256), 0, stream>>>(x, wqkv, wgate, wo, nb, xb, wallb, wob, nbb);
  k_gemm0<<<dim3(1024), dim3(512), 0, stream>>>(xb, wallb, qs, ksb, vsb, gateb, gbias);
  k_attn<<<dim3(128, 8), dim3(512), 0, stream>>>(qs, ksb, vsb, gateb, mask, nbb, wag);
  k_gemm1<<<dim3(256, 2), dim3(256), 0, stream>>>(wag, wob, outp, bo);
}